// Round 10
// baseline (22.928 us; speedup 1.0000x reference)
//
#include <hip/hip_runtime.h>
#include <math.h>

#define NB 512
#define HW 169
#define NA 5
#define NCH 125
#define CELLS 64                          // cells per block
#define BLOCK (CELLS * NA)                // 320 threads = 5 waves
#define NBLOCKS ((NB * HW) / CELLS)       // 1352 exactly
#define SLAB_F4 ((CELLS * NCH) / 4)       // 2000 float4 per block slab (32 KB)
#define REC 8                             // padded per-block record (dwords)

// T is streamed CONTIGUOUSLY (float4, zero per-element index math) into LDS raw;
// compute threads (5 per cell) read needed fields from LDS. This converts the
// 26 MB scattered-line HBM pattern (measured ~1.9 TB/s) into a 43.3 MB pure
// sequential stream, without R4's div/mod VALU bomb (its actual failure mode).
__global__ __launch_bounds__(BLOCK) void yolo_loss_main(
    const float* __restrict__ P,    // [B][125][169] (channel-major)
    const float* __restrict__ T,    // [B][169][125]
    const float* __restrict__ ANC,  // [5][2]
    float* __restrict__ brec)       // [NBLOCKS][REC]
{
    __shared__ float sT[CELLS * NCH];     // 32 KB raw slab
    int t = threadIdx.x;

    // ---- phase 1: contiguous slab copy, no index math beyond li = t + k*320
    {
        const float4* T4 = (const float4*)T + (size_t)blockIdx.x * SLAB_F4;
        float4* s4 = (float4*)sT;
#pragma unroll
        for (int k = 0; k < 7; ++k) {
            int li = t + k * BLOCK;
            if (li < SLAB_F4) s4[li] = T4[li];
        }
    }

    // ---- P loads (independent of LDS): 5 threads/cell, own anchor's 4 logits
    int cl = t / NA;                      // local cell 0..63 (magic-mul div)
    int a  = t - cl * NA;                 // own anchor slot 0..4
    int cell = blockIdx.x * CELLS + cl;
    int b  = cell / HW;
    int hw = cell - b * HW;
    const float* Pb = P + (size_t)b * (NCH * HW) + hw + (a * 25 + 21) * HW;
    float rx = Pb[0];
    float ry = Pb[HW];
    float rw = Pb[2 * HW];
    float rh = Pb[3 * HW];
    float aw = ANC[2 * a], ah = ANC[2 * a + 1];

    __syncthreads();

    // ---- phase 2: gt fields from LDS (5-lane broadcast per cell on box reads)
    const float* sc = sT + cl * NCH;
    float g[20];
#pragma unroll
    for (int j = 0; j < NA; ++j) {
        g[j * 4 + 0] = sc[j * 25 + 21];
        g[j * 4 + 1] = sc[j * 25 + 22];
        g[j * 4 + 2] = sc[j * 25 + 23];
        g[j * 4 + 3] = sc[j * 25 + 24];
    }
    float conf = sc[a * 25 + 20];
    float gxa  = sc[a * 25 + 21];
    float gya  = sc[a * 25 + 22];
    float gwa  = sc[a * 25 + 23];
    float gha  = sc[a * 25 + 24];

    // ---- phase 3: transforms + one IoU row (anchor a vs 5 gt) + argmax
    float px = 1.0f / (1.0f + expf(-rx));
    float py = 1.0f / (1.0f + expf(-ry));
    float pw = expf(rw);
    float ph = expf(rh);

    float ax1 = px - aw * 0.5f, ax2 = px + aw * 0.5f;
    float ay1 = py - ah * 0.5f, ay2 = py + ah * 0.5f;
    float area_a = (ax2 - ax1) * (ay2 - ay1);
    float best = -1.0f; int bestj = 0;
#pragma unroll
    for (int j = 0; j < NA; ++j) {
        float bx = g[j * 4 + 0], by = g[j * 4 + 1];
        float bw = g[j * 4 + 2], bh = g[j * 4 + 3];
        float bx1 = bx - bw * 0.5f, bx2 = bx + bw * 0.5f;
        float by1 = by - bh * 0.5f, by2 = by + bh * 0.5f;
        float iw = fmaxf(fminf(ax2, bx2) - fmaxf(ax1, bx1), 0.0f);
        float ih = fmaxf(fminf(ay2, by2) - fmaxf(ay1, by1), 0.0f);
        float inter = iw * ih;
        float area_b = (bx2 - bx1) * (by2 - by1);
        float iou = inter / (area_a + area_b - inter + 1e-10f);
        if (iou > best) { best = iou; bestj = j; }     // strict > == first-max ties
    }
    int cmask = 1 << bestj;

    float dx = px - gxa, dy = py - gya, dw = pw - gwa, dh = ph - gha;
    float contrib = conf * conf * (dx * dx + dy * dy + dw * dw + dh * dh);

    // ---- phase 4: 5 anchor bins, wave shuffle -> LDS cross-wave -> 32-B record
    __shared__ float sred[5][NA];
    __shared__ int smask[5];
    int lane = t & 63, wid = t >> 6;      // 5 waves

#pragma unroll
    for (int i = 0; i < NA; ++i) {
        float v = (a == i) ? contrib : 0.0f;
        for (int off = 32; off; off >>= 1) v += __shfl_down(v, off, 64);
        if (lane == 0) sred[wid][i] = v;
    }
    for (int off = 32; off; off >>= 1) cmask |= __shfl_down(cmask, off, 64);
    if (lane == 0) smask[wid] = cmask;
    __syncthreads();

    if (t == 0) {
        int m = smask[0] | smask[1] | smask[2] | smask[3] | smask[4];
        float s[NA];
#pragma unroll
        for (int i = 0; i < NA; ++i)
            s[i] = sred[0][i] + sred[1][i] + sred[2][i] + sred[3][i] + sred[4][i];
        float4* r4 = (float4*)(brec + blockIdx.x * REC);
        r4[0] = make_float4(s[0], s[1], s[2], s[3]);
        r4[1] = make_float4(s[4], __int_as_float(m), 0.0f, 0.0f);
    }
}

__global__ __launch_bounds__(256) void yolo_loss_final(
    const float* __restrict__ brec, float* __restrict__ out)
{
    __shared__ double sredd[4][NA];
    __shared__ int smaskd[4];
    int t = threadIdx.x, lane = t & 63, wid = t >> 6;
    const float4* r4 = (const float4*)brec;

    double s[NA] = {0, 0, 0, 0, 0};
    int m = 0;
    for (int e = t; e < NBLOCKS; e += 256) {
        float4 lo = r4[e * 2];
        float4 hi = r4[e * 2 + 1];
        s[0] += (double)lo.x; s[1] += (double)lo.y;
        s[2] += (double)lo.z; s[3] += (double)lo.w;
        s[4] += (double)hi.x;
        m |= __float_as_int(hi.y);
    }
#pragma unroll
    for (int i = 0; i < NA; ++i)
        for (int off = 32; off; off >>= 1) s[i] += __shfl_down(s[i], off, 64);
    for (int off = 32; off; off >>= 1) m |= __shfl_down(m, off, 64);
    if (lane == 0) {
#pragma unroll
        for (int i = 0; i < NA; ++i) sredd[wid][i] = s[i];
        smaskd[wid] = m;
    }
    __syncthreads();

    if (t == 0) {
        int mm = smaskd[0] | smaskd[1] | smaskd[2] | smaskd[3];
        double tot = 0.0;
#pragma unroll
        for (int i = 0; i < NA; ++i)
            if ((mm >> i) & 1)
                tot += sredd[0][i] + sredd[1][i] + sredd[2][i] + sredd[3][i];
        out[0] = (float)((5.0 / 512.0) * tot);
    }
}

extern "C" void kernel_launch(void* const* d_in, const int* in_sizes, int n_in,
                              void* d_out, int out_size, void* d_ws, size_t ws_size,
                              hipStream_t stream) {
    const float* P   = (const float*)d_in[0];
    const float* T   = (const float*)d_in[1];
    const float* ANC = (const float*)d_in[2];
    float* out = (float*)d_out;

    float* brec = (float*)d_ws;   // NBLOCKS * REC floats = 43 KB

    yolo_loss_main<<<NBLOCKS, BLOCK, 0, stream>>>(P, T, ANC, brec);
    yolo_loss_final<<<1, 256, 0, stream>>>(brec, out);
}